// Round 4
// baseline (658.888 us; speedup 1.0000x reference)
//
#include <hip/hip_runtime.h>
#include <hip/hip_bf16.h>

// CausalSelfAttention on gfx950 — round 4.
// Round-3 evidence: attn is latency-bound (MfmaUtil 5.3%, occupancy 13.9% ~ 1.1
// blocks/CU); dbuf+bigger tiles didn't help. Round-4 attn removes the latency
// sources: no K/V LDS staging (B-fragments loaded directly from global as
// dwordx4 — K rows contiguous along d, V^T rows contiguous along t), no
// __syncthreads in the k-loop, static-max softmax (no max shuffles, no alpha
// rescale), l-reduction deferred to epilogue (zero shuffles in loop). LDS holds
// only the per-wave P transpose (9.2 KB/block). GEMMs unchanged.

typedef unsigned short u16;
typedef __attribute__((ext_vector_type(8))) short short8;
typedef __attribute__((ext_vector_type(4))) float f32x4;

#define N_HEADS 16
#define HEAD_DIM 64
#define TSEQ 2048
#define BATCH 4
#define MROWS (BATCH * TSEQ)   // 8192
#define N3 3072                // 3*D_MODEL

__device__ __forceinline__ void cp16(const u16* g, u16* l) {
  __builtin_amdgcn_global_load_lds((const __attribute__((address_space(1))) void*)g,
                                   (__attribute__((address_space(3))) void*)l, 16, 0, 0);
}

__device__ __forceinline__ f32x4 mfma16(short8 a, short8 b, f32x4 c) {
  return __builtin_amdgcn_mfma_f32_16x16x32_bf16(a, b, c, 0, 0, 0);
}

__device__ __forceinline__ u16 f2b(float f) {
  __hip_bfloat16 h = __float2bfloat16(f);
  return *reinterpret_cast<u16*>(&h);
}

// ------------------------------------------------------------ fp32 -> bf16
__global__ __launch_bounds__(256) void cvt_f32_bf16(const float* __restrict__ src,
                                                    u16* __restrict__ dst, int n4) {
  int i = blockIdx.x * 256 + threadIdx.x;
  if (i < n4) {
    float4 v = *(const float4*)(src + (size_t)i * 4);
    u16* d = dst + (size_t)i * 4;
    d[0] = f2b(v.x); d[1] = f2b(v.y); d[2] = f2b(v.z); d[3] = f2b(v.w);
  }
}

// ------------------------------------------- fp32 [R][Cn] -> bf16 [Cn][R]
__global__ void transpose_cvt(const float* __restrict__ src, u16* __restrict__ dst,
                              int R, int Cn) {
  __shared__ float tile[32][33];
  int c0 = blockIdx.x * 32, r0 = blockIdx.y * 32;
  for (int i = threadIdx.y; i < 32; i += 8)
    tile[i][threadIdx.x] = src[(size_t)(r0 + i) * Cn + c0 + threadIdx.x];
  __syncthreads();
  for (int i = threadIdx.y; i < 32; i += 8)
    dst[(size_t)(c0 + i) * R + r0 + threadIdx.x] = f2b(tile[threadIdx.x][i]);
}

// ---------------------------------------------------------------- GEMM core
__device__ __forceinline__ void gemm128_core(const u16* __restrict__ A,
                                             const u16* __restrict__ Bt,
                                             int m0, int n0,
                                             u16* Asm, u16* Bsm,
                                             f32x4 acc[4][4]) {
  const int tid = threadIdx.x;
  const int w = tid >> 6;
  const int lane = tid & 63;
  const int quad = lane >> 4;
  const int l16 = lane & 15;
  const int wm = (w >> 1) * 64;
  const int wn = (w & 1) * 64;

#pragma unroll
  for (int i = 0; i < 4; ++i)
#pragma unroll
    for (int j = 0; j < 4; ++j) acc[i][j] = (f32x4){0.f, 0.f, 0.f, 0.f};

  for (int k0 = 0; k0 < 1024; k0 += 32) {
    __syncthreads();
#pragma unroll
    for (int p = 0; p < 2; ++p) {
      int s = p * 256 + tid;
      int row = s >> 2;
      int c4 = (s & 3) ^ ((row >> 1) & 3);
      cp16(A + (size_t)(m0 + row) * 1024 + k0 + c4 * 8,
           Asm + (size_t)(p * 256 + w * 64) * 8);
      cp16(Bt + (size_t)(n0 + row) * 1024 + k0 + c4 * 8,
           Bsm + (size_t)(p * 256 + w * 64) * 8);
    }
    __syncthreads();

    short8 a[4], b[4];
#pragma unroll
    for (int i = 0; i < 4; ++i) {
      int row = wm + i * 16 + l16;
      int c4 = quad ^ ((row >> 1) & 3);
      a[i] = *(const short8*)(Asm + row * 32 + c4 * 8);
    }
#pragma unroll
    for (int j = 0; j < 4; ++j) {
      int row = wn + j * 16 + l16;
      int c4 = quad ^ ((row >> 1) & 3);
      b[j] = *(const short8*)(Bsm + row * 32 + c4 * 8);
    }
#pragma unroll
    for (int i = 0; i < 4; ++i)
#pragma unroll
      for (int j = 0; j < 4; ++j)
        acc[i][j] = mfma16(a[i], b[j], acc[i][j]);
  }
}

// ---------------------------------------------------------------- QKV GEMM
__global__ __launch_bounds__(256) void gemm_qkv_kernel(
    const u16* __restrict__ x, const u16* __restrict__ Wt,
    const float* __restrict__ bias,
    u16* __restrict__ qb, u16* __restrict__ kb, u16* __restrict__ vtb) {
  __shared__ __align__(16) u16 Asm[128 * 32];
  __shared__ __align__(16) u16 Bsm[128 * 32];
  f32x4 acc[4][4];
  const int m0 = blockIdx.y * 128;
  const int n0 = blockIdx.x * 128;
  gemm128_core(x, Wt, m0, n0, Asm, Bsm, acc);

  const int tid = threadIdx.x;
  const int w = tid >> 6, lane = tid & 63, quad = lane >> 4, l16 = lane & 15;
  const int wm = (w >> 1) * 64, wn = (w & 1) * 64;
#pragma unroll
  for (int j = 0; j < 4; ++j) {
    int col = n0 + wn + j * 16 + l16;
    float bv = bias[col];
    int which = col >> 10;     // 0=q 1=k 2=v
    int rem = col & 1023;
    int h = rem >> 6, d = rem & 63;
#pragma unroll
    for (int i = 0; i < 4; ++i) {
#pragma unroll
      for (int r = 0; r < 4; ++r) {
        int m = m0 + wm + i * 16 + quad * 4 + r;
        int b_ = m >> 11, t = m & 2047;
        int bh = b_ * N_HEADS + h;
        u16 o = f2b(acc[i][j][r] + bv);
        if (which == 0)
          qb[((size_t)(bh * TSEQ + t) << 6) + d] = o;
        else if (which == 1)
          kb[((size_t)(bh * TSEQ + t) << 6) + d] = o;
        else
          vtb[((size_t)((bh << 6) + d)) * TSEQ + t] = o;
      }
    }
  }
}

// ---------------------------------------------------------------- attention
// One block per (64-row q-tile, bh); 4 waves, wave w owns q rows qt*64+w*16..+15.
// No __syncthreads in the k-loop; K/V fragments loaded directly from global.
__global__ __launch_bounds__(256, 3) void attn_kernel(const u16* __restrict__ qb,
                                                      const u16* __restrict__ kb,
                                                      const u16* __restrict__ vtb,
                                                      u16* __restrict__ ob) {
  const int qt = (TSEQ / 64 - 1) - blockIdx.x;  // 31..0 — heavy blocks first
  const int bh = blockIdx.y;                    // 0..63
  __shared__ __align__(16) u16 Psm[4 * 16 * 72];  // per-wave P, stride 72
  const int tid = threadIdx.x;
  const int w = tid >> 6, lane = tid & 63, quad = lane >> 4, l16 = lane & 15;
  const int qrow0 = qt * 64 + w * 16;   // this wave's first q row

  // Q A-fragments (rows l16, k = quad*8.. / 32+quad*8..), kept in registers
  const u16* qr = qb + ((size_t)(bh * TSEQ + qrow0 + l16)) * 64;
  const short8 qf0 = *(const short8*)(qr + quad * 8);
  const short8 qf1 = *(const short8*)(qr + 32 + quad * 8);

  f32x4 o[4];
#pragma unroll
  for (int j = 0; j < 4; ++j) o[j] = (f32x4){0.f, 0.f, 0.f, 0.f};
  float lp[4] = {0.f, 0.f, 0.f, 0.f};   // per-lane partial row sums
  const float cexp = 0.18033688011112042f;  // (1/sqrt(64)) * log2(e)
  const float M = 10.0f;                    // static softmax shift (safe: |s*cexp|<~10)

  const u16* kb_bh = kb + (size_t)bh * TSEQ * 64;
  const u16* vt_bh = vtb + (size_t)bh * 64 * TSEQ;
  u16* pw = Psm + w * 16 * 72;

  for (int kt = 0; kt <= qt; ++kt) {
    // ---- S = Q K^T : B-frags straight from global (K row j*16+l16, contig d)
    const u16* kt_base = kb_bh + (size_t)(kt * 64) * 64;
    f32x4 s[4];
#pragma unroll
    for (int j = 0; j < 4; ++j) {
      const u16* krow = kt_base + (size_t)(j * 16 + l16) * 64;
      short8 k0 = *(const short8*)(krow + quad * 8);
      short8 k1 = *(const short8*)(krow + 32 + quad * 8);
      f32x4 z = (f32x4){0.f, 0.f, 0.f, 0.f};
      z = mfma16(qf0, k0, z);
      z = mfma16(qf1, k1, z);
      s[j] = z;
    }
    if (kt == qt) {  // diagonal tile: mask k > q
#pragma unroll
      for (int j = 0; j < 4; ++j) {
        int k = j * 16 + l16;           // key offset within tile == global offset here
#pragma unroll
        for (int r = 0; r < 4; ++r)
          if (k > w * 16 + quad * 4 + r) s[j][r] = -1e30f;
      }
    }

    // ---- static-max softmax: p = exp2(s*cexp - M); in-lane partial sums
#pragma unroll
    for (int j = 0; j < 4; ++j) {
#pragma unroll
      for (int r = 0; r < 4; ++r) {
        float p = __builtin_amdgcn_exp2f(__builtin_fmaf(s[j][r], cexp, -M));
        lp[r] += p;
        pw[(quad * 4 + r) * 72 + j * 16 + l16] = f2b(p);  // C-layout -> LDS
      }
    }
    asm volatile("s_waitcnt lgkmcnt(0)" ::: "memory");

    // ---- O += P V : P A-frags from LDS, V B-frags straight from global
    short8 ap0 = *(const short8*)(pw + l16 * 72 + quad * 8);
    short8 ap1 = *(const short8*)(pw + l16 * 72 + 32 + quad * 8);
    const u16* vt_kt = vt_bh + kt * 64;
#pragma unroll
    for (int j = 0; j < 4; ++j) {
      const u16* vrow = vt_kt + (size_t)(j * 16 + l16) * TSEQ;  // V^T row d, contig t
      short8 v0 = *(const short8*)(vrow + quad * 8);
      short8 v1 = *(const short8*)(vrow + 32 + quad * 8);
      o[j] = mfma16(ap0, v0, o[j]);
      o[j] = mfma16(ap1, v1, o[j]);
    }
  }

  // ---- epilogue: reduce l across the 16 lanes sharing quad, normalize, store
#pragma unroll
  for (int r = 0; r < 4; ++r) {
    lp[r] += __shfl_xor(lp[r], 1);
    lp[r] += __shfl_xor(lp[r], 2);
    lp[r] += __shfl_xor(lp[r], 4);
    lp[r] += __shfl_xor(lp[r], 8);
  }
  const int b_ = bh >> 4, h = bh & 15;
#pragma unroll
  for (int j = 0; j < 4; ++j)
#pragma unroll
    for (int r = 0; r < 4; ++r) {
      int t = qt * 64 + w * 16 + quad * 4 + r;
      int d = j * 16 + l16;
      ob[((size_t)(b_ * TSEQ + t)) * 1024 + h * 64 + d] = f2b(o[j][r] / lp[r]);
    }
}

// ------------------------------------------------------- out GEMM (fp32 out)
__global__ __launch_bounds__(256) void gemm_out_kernel(
    const u16* __restrict__ attn, const u16* __restrict__ Wt,
    const float* __restrict__ bias, float* __restrict__ out) {
  __shared__ __align__(16) u16 Asm[128 * 32];
  __shared__ __align__(16) u16 Bsm[128 * 32];
  f32x4 acc[4][4];
  const int m0 = blockIdx.y * 128;
  const int n0 = blockIdx.x * 128;
  gemm128_core(attn, Wt, m0, n0, Asm, Bsm, acc);

  const int tid = threadIdx.x;
  const int w = tid >> 6, lane = tid & 63, quad = lane >> 4, l16 = lane & 15;
  const int wm = (w >> 1) * 64, wn = (w & 1) * 64;
#pragma unroll
  for (int j = 0; j < 4; ++j) {
    int col = n0 + wn + j * 16 + l16;
    float bv = bias[col];
#pragma unroll
    for (int i = 0; i < 4; ++i)
#pragma unroll
      for (int r = 0; r < 4; ++r) {
        int m = m0 + wm + i * 16 + quad * 4 + r;
        out[(size_t)m * 1024 + col] = acc[i][j][r] + bv;
      }
  }
}

// ---------------------------------------------------------------- launcher
extern "C" void kernel_launch(void* const* d_in, const int* in_sizes, int n_in,
                              void* d_out, int out_size, void* d_ws, size_t ws_size,
                              hipStream_t stream) {
  const float* x    = (const float*)d_in[0];   // [8192][1024] fp32
  const float* Wqkv = (const float*)d_in[1];   // [1024][3072] fp32
  const float* bqkv = (const float*)d_in[2];   // [3072] fp32
  const float* Wout = (const float*)d_in[3];   // [1024][1024] fp32
  const float* bout = (const float*)d_in[4];   // [1024] fp32
  float* out = (float*)d_out;                  // [8192][1024] fp32

  u16* ws = (u16*)d_ws;
  u16* xb     = ws;                                  // 8M   bf16 x
  u16* wqkv_t = xb + (size_t)MROWS * 1024;           // 3M   [3072][1024]
  u16* wout_t = wqkv_t + (size_t)N3 * 1024;          // 1M   [1024][1024]
  u16* qbuf   = wout_t + (size_t)1024 * 1024;        // 8M   [bh][t][d]
  u16* kbuf   = qbuf + (size_t)MROWS * 1024;         // 8M   [bh][t][d]
  u16* vtbuf  = kbuf + (size_t)MROWS * 1024;         // 8M   [bh][d][t]
  u16* obuf   = vtbuf + (size_t)MROWS * 1024;        // 8M   [b][t][c]
  (void)ws_size; (void)n_in; (void)in_sizes; (void)out_size;

  int n4 = MROWS * 1024 / 4;
  cvt_f32_bf16<<<(n4 + 255) / 256, 256, 0, stream>>>(x, xb, n4);
  transpose_cvt<<<dim3(N3 / 32, 1024 / 32), dim3(32, 8), 0, stream>>>(Wqkv, wqkv_t, 1024, N3);
  transpose_cvt<<<dim3(1024 / 32, 1024 / 32), dim3(32, 8), 0, stream>>>(Wout, wout_t, 1024, 1024);
  gemm_qkv_kernel<<<dim3(N3 / 128, MROWS / 128), 256, 0, stream>>>(xb, wqkv_t, bqkv, qbuf, kbuf, vtbuf);
  attn_kernel<<<dim3(TSEQ / 64, BATCH * N_HEADS), 256, 0, stream>>>(qbuf, kbuf, vtbuf, obuf);
  gemm_out_kernel<<<dim3(1024 / 128, MROWS / 128), 256, 0, stream>>>(obuf, wout_t, bout, out);
}

// Round 5
// 655.946 us; speedup vs baseline: 1.0045x; 1.0045x over previous
//
#include <hip/hip_runtime.h>
#include <hip/hip_bf16.h>

// CausalSelfAttention on gfx950 — round 5.
// Evidence r2-r4: attn wall = serial-iters × exposed latency; staging via LDS
// (r2/r3, two-barrier vmcnt(0) drain) and dependent global loads (r4) both
// expose ~2000+ cyc/iter. Round-5 attn: K/V fragments double-buffered in
// REGISTERS, prefetched one k-tile ahead (loads for kt+1 issued before compute
// of kt) — chain shrinks to compute-only. Keeps r4's static-max softmax (no
// shuffles in loop), no __syncthreads, independent waves. 2x-unrolled loop
// with explicit buffer variables (no dynamic reg indexing). GEMMs unchanged.

typedef unsigned short u16;
typedef __attribute__((ext_vector_type(8))) short short8;
typedef __attribute__((ext_vector_type(4))) float f32x4;

#define N_HEADS 16
#define HEAD_DIM 64
#define TSEQ 2048
#define BATCH 4
#define MROWS (BATCH * TSEQ)   // 8192
#define N3 3072                // 3*D_MODEL

__device__ __forceinline__ void cp16(const u16* g, u16* l) {
  __builtin_amdgcn_global_load_lds((const __attribute__((address_space(1))) void*)g,
                                   (__attribute__((address_space(3))) void*)l, 16, 0, 0);
}

__device__ __forceinline__ f32x4 mfma16(short8 a, short8 b, f32x4 c) {
  return __builtin_amdgcn_mfma_f32_16x16x32_bf16(a, b, c, 0, 0, 0);
}

__device__ __forceinline__ u16 f2b(float f) {
  __hip_bfloat16 h = __float2bfloat16(f);
  return *reinterpret_cast<u16*>(&h);
}

// ------------------------------------------------------------ fp32 -> bf16
__global__ __launch_bounds__(256) void cvt_f32_bf16(const float* __restrict__ src,
                                                    u16* __restrict__ dst, int n4) {
  int i = blockIdx.x * 256 + threadIdx.x;
  if (i < n4) {
    float4 v = *(const float4*)(src + (size_t)i * 4);
    u16* d = dst + (size_t)i * 4;
    d[0] = f2b(v.x); d[1] = f2b(v.y); d[2] = f2b(v.z); d[3] = f2b(v.w);
  }
}

// ------------------------------------------- fp32 [R][Cn] -> bf16 [Cn][R]
__global__ void transpose_cvt(const float* __restrict__ src, u16* __restrict__ dst,
                              int R, int Cn) {
  __shared__ float tile[32][33];
  int c0 = blockIdx.x * 32, r0 = blockIdx.y * 32;
  for (int i = threadIdx.y; i < 32; i += 8)
    tile[i][threadIdx.x] = src[(size_t)(r0 + i) * Cn + c0 + threadIdx.x];
  __syncthreads();
  for (int i = threadIdx.y; i < 32; i += 8)
    dst[(size_t)(c0 + i) * R + r0 + threadIdx.x] = f2b(tile[threadIdx.x][i]);
}

// ---------------------------------------------------------------- GEMM core
__device__ __forceinline__ void gemm128_core(const u16* __restrict__ A,
                                             const u16* __restrict__ Bt,
                                             int m0, int n0,
                                             u16* Asm, u16* Bsm,
                                             f32x4 acc[4][4]) {
  const int tid = threadIdx.x;
  const int w = tid >> 6;
  const int lane = tid & 63;
  const int quad = lane >> 4;
  const int l16 = lane & 15;
  const int wm = (w >> 1) * 64;
  const int wn = (w & 1) * 64;

#pragma unroll
  for (int i = 0; i < 4; ++i)
#pragma unroll
    for (int j = 0; j < 4; ++j) acc[i][j] = (f32x4){0.f, 0.f, 0.f, 0.f};

  for (int k0 = 0; k0 < 1024; k0 += 32) {
    __syncthreads();
#pragma unroll
    for (int p = 0; p < 2; ++p) {
      int s = p * 256 + tid;
      int row = s >> 2;
      int c4 = (s & 3) ^ ((row >> 1) & 3);
      cp16(A + (size_t)(m0 + row) * 1024 + k0 + c4 * 8,
           Asm + (size_t)(p * 256 + w * 64) * 8);
      cp16(Bt + (size_t)(n0 + row) * 1024 + k0 + c4 * 8,
           Bsm + (size_t)(p * 256 + w * 64) * 8);
    }
    __syncthreads();

    short8 a[4], b[4];
#pragma unroll
    for (int i = 0; i < 4; ++i) {
      int row = wm + i * 16 + l16;
      int c4 = quad ^ ((row >> 1) & 3);
      a[i] = *(const short8*)(Asm + row * 32 + c4 * 8);
    }
#pragma unroll
    for (int j = 0; j < 4; ++j) {
      int row = wn + j * 16 + l16;
      int c4 = quad ^ ((row >> 1) & 3);
      b[j] = *(const short8*)(Bsm + row * 32 + c4 * 8);
    }
#pragma unroll
    for (int i = 0; i < 4; ++i)
#pragma unroll
      for (int j = 0; j < 4; ++j)
        acc[i][j] = mfma16(a[i], b[j], acc[i][j]);
  }
}

// ---------------------------------------------------------------- QKV GEMM
__global__ __launch_bounds__(256) void gemm_qkv_kernel(
    const u16* __restrict__ x, const u16* __restrict__ Wt,
    const float* __restrict__ bias,
    u16* __restrict__ qb, u16* __restrict__ kb, u16* __restrict__ vtb) {
  __shared__ __align__(16) u16 Asm[128 * 32];
  __shared__ __align__(16) u16 Bsm[128 * 32];
  f32x4 acc[4][4];
  const int m0 = blockIdx.y * 128;
  const int n0 = blockIdx.x * 128;
  gemm128_core(x, Wt, m0, n0, Asm, Bsm, acc);

  const int tid = threadIdx.x;
  const int w = tid >> 6, lane = tid & 63, quad = lane >> 4, l16 = lane & 15;
  const int wm = (w >> 1) * 64, wn = (w & 1) * 64;
#pragma unroll
  for (int j = 0; j < 4; ++j) {
    int col = n0 + wn + j * 16 + l16;
    float bv = bias[col];
    int which = col >> 10;     // 0=q 1=k 2=v
    int rem = col & 1023;
    int h = rem >> 6, d = rem & 63;
#pragma unroll
    for (int i = 0; i < 4; ++i) {
#pragma unroll
      for (int r = 0; r < 4; ++r) {
        int m = m0 + wm + i * 16 + quad * 4 + r;
        int b_ = m >> 11, t = m & 2047;
        int bh = b_ * N_HEADS + h;
        u16 o = f2b(acc[i][j][r] + bv);
        if (which == 0)
          qb[((size_t)(bh * TSEQ + t) << 6) + d] = o;
        else if (which == 1)
          kb[((size_t)(bh * TSEQ + t) << 6) + d] = o;
        else
          vtb[((size_t)((bh << 6) + d)) * TSEQ + t] = o;
      }
    }
  }
}

// ---------------------------------------------------------------- attention
struct KVFrag {            // one k-tile's fragments for one wave (96 VGPRs)
  short8 k[4][2];          // K rows j*16+l16, halves of d
  short8 v[4][2];          // V^T rows j*16+l16 (=d), halves of t
};

__device__ __forceinline__ void kv_load(KVFrag& f, const u16* __restrict__ kb_bh,
                                        const u16* __restrict__ vt_bh, int kt,
                                        int l16, int quad) {
  const u16* kt_base = kb_bh + (size_t)(kt * 64) * 64;
  const u16* vt_kt = vt_bh + kt * 64;
#pragma unroll
  for (int j = 0; j < 4; ++j) {
    const u16* krow = kt_base + (size_t)(j * 16 + l16) * 64;
    f.k[j][0] = *(const short8*)(krow + quad * 8);
    f.k[j][1] = *(const short8*)(krow + 32 + quad * 8);
    const u16* vrow = vt_kt + (size_t)(j * 16 + l16) * TSEQ;
    f.v[j][0] = *(const short8*)(vrow + quad * 8);
    f.v[j][1] = *(const short8*)(vrow + 32 + quad * 8);
  }
}

// One block per (64-row q-tile, bh); 4 independent waves; no barriers in loop.
__global__ __launch_bounds__(256, 2) void attn_kernel(const u16* __restrict__ qb,
                                                      const u16* __restrict__ kb,
                                                      const u16* __restrict__ vtb,
                                                      u16* __restrict__ ob) {
  const int qt = (TSEQ / 64 - 1) - blockIdx.x;  // 31..0 — heavy blocks first
  const int bh = blockIdx.y;                    // 0..63
  __shared__ __align__(16) u16 Psm[4 * 16 * 72];  // per-wave P, stride 72
  const int tid = threadIdx.x;
  const int w = tid >> 6, lane = tid & 63, quad = lane >> 4, l16 = lane & 15;
  const int qrow0 = qt * 64 + w * 16;

  const u16* qr = qb + ((size_t)(bh * TSEQ + qrow0 + l16)) * 64;
  const short8 qf0 = *(const short8*)(qr + quad * 8);
  const short8 qf1 = *(const short8*)(qr + 32 + quad * 8);

  f32x4 o[4];
#pragma unroll
  for (int j = 0; j < 4; ++j) o[j] = (f32x4){0.f, 0.f, 0.f, 0.f};
  float lp[4] = {0.f, 0.f, 0.f, 0.f};
  const float cexp = 0.18033688011112042f;  // (1/sqrt(64)) * log2(e)
  const float M = 10.0f;                    // static softmax shift

  const u16* kb_bh = kb + (size_t)bh * TSEQ * 64;
  const u16* vt_bh = vtb + (size_t)bh * 64 * TSEQ;
  u16* pw = Psm + w * 16 * 72;

  // compute one k-tile entirely from registers (f), P via per-wave LDS region
#define COMPUTE(f, kt_)                                                        \
  do {                                                                         \
    _Pragma("unroll")                                                          \
    for (int j = 0; j < 4; ++j) {                                              \
      f32x4 z = (f32x4){0.f, 0.f, 0.f, 0.f};                                   \
      z = mfma16(qf0, (f).k[j][0], z);                                         \
      z = mfma16(qf1, (f).k[j][1], z);                                         \
      if ((kt_) == qt) { /* diagonal tile: mask k > q */                       \
        int k_ = j * 16 + l16;                                                 \
        _Pragma("unroll")                                                      \
        for (int r = 0; r < 4; ++r)                                            \
          if (k_ > w * 16 + quad * 4 + r) z[r] = -1e30f;                       \
      }                                                                        \
      _Pragma("unroll")                                                        \
      for (int r = 0; r < 4; ++r) {                                            \
        float p_ = __builtin_amdgcn_exp2f(__builtin_fmaf(z[r], cexp, -M));     \
        lp[r] += p_;                                                           \
        pw[(quad * 4 + r) * 72 + j * 16 + l16] = f2b(p_);                      \
      }                                                                        \
    }                                                                          \
    asm volatile("s_waitcnt lgkmcnt(0)" ::: "memory");                         \
    {                                                                          \
      short8 ap0 = *(const short8*)(pw + l16 * 72 + quad * 8);                 \
      short8 ap1 = *(const short8*)(pw + l16 * 72 + 32 + quad * 8);            \
      _Pragma("unroll")                                                        \
      for (int j = 0; j < 4; ++j) {                                            \
        o[j] = mfma16(ap0, (f).v[j][0], o[j]);                                 \
        o[j] = mfma16(ap1, (f).v[j][1], o[j]);                                 \
      }                                                                        \
    }                                                                          \
  } while (0)

  KVFrag fA, fB;
  kv_load(fA, kb_bh, vt_bh, 0, l16, quad);
  int kt = 0;
  while (true) {
    // even iter: consume fA, prefetch kt+1 into fB
    if (kt + 1 <= qt) kv_load(fB, kb_bh, vt_bh, kt + 1, l16, quad);
    COMPUTE(fA, kt);
    if (++kt > qt) break;
    // odd iter: consume fB, prefetch kt+1 into fA
    if (kt + 1 <= qt) kv_load(fA, kb_bh, vt_bh, kt + 1, l16, quad);
    COMPUTE(fB, kt);
    if (++kt > qt) break;
  }
#undef COMPUTE

  // epilogue: reduce l across the 16 lanes sharing quad, normalize, store
#pragma unroll
  for (int r = 0; r < 4; ++r) {
    lp[r] += __shfl_xor(lp[r], 1);
    lp[r] += __shfl_xor(lp[r], 2);
    lp[r] += __shfl_xor(lp[r], 4);
    lp[r] += __shfl_xor(lp[r], 8);
  }
  const int b_ = bh >> 4, h = bh & 15;
#pragma unroll
  for (int j = 0; j < 4; ++j)
#pragma unroll
    for (int r = 0; r < 4; ++r) {
      int t = qt * 64 + w * 16 + quad * 4 + r;
      int d = j * 16 + l16;
      ob[((size_t)(b_ * TSEQ + t)) * 1024 + h * 64 + d] = f2b(o[j][r] / lp[r]);
    }
}

// ------------------------------------------------------- out GEMM (fp32 out)
__global__ __launch_bounds__(256) void gemm_out_kernel(
    const u16* __restrict__ attn, const u16* __restrict__ Wt,
    const float* __restrict__ bias, float* __restrict__ out) {
  __shared__ __align__(16) u16 Asm[128 * 32];
  __shared__ __align__(16) u16 Bsm[128 * 32];
  f32x4 acc[4][4];
  const int m0 = blockIdx.y * 128;
  const int n0 = blockIdx.x * 128;
  gemm128_core(attn, Wt, m0, n0, Asm, Bsm, acc);

  const int tid = threadIdx.x;
  const int w = tid >> 6, lane = tid & 63, quad = lane >> 4, l16 = lane & 15;
  const int wm = (w >> 1) * 64, wn = (w & 1) * 64;
#pragma unroll
  for (int j = 0; j < 4; ++j) {
    int col = n0 + wn + j * 16 + l16;
    float bv = bias[col];
#pragma unroll
    for (int i = 0; i < 4; ++i)
#pragma unroll
      for (int r = 0; r < 4; ++r) {
        int m = m0 + wm + i * 16 + quad * 4 + r;
        out[(size_t)m * 1024 + col] = acc[i][j][r] + bv;
      }
  }
}

// ---------------------------------------------------------------- launcher
extern "C" void kernel_launch(void* const* d_in, const int* in_sizes, int n_in,
                              void* d_out, int out_size, void* d_ws, size_t ws_size,
                              hipStream_t stream) {
  const float* x    = (const float*)d_in[0];   // [8192][1024] fp32
  const float* Wqkv = (const float*)d_in[1];   // [1024][3072] fp32
  const float* bqkv = (const float*)d_in[2];   // [3072] fp32
  const float* Wout = (const float*)d_in[3];   // [1024][1024] fp32
  const float* bout = (const float*)d_in[4];   // [1024] fp32
  float* out = (float*)d_out;                  // [8192][1024] fp32

  u16* ws = (u16*)d_ws;
  u16* xb     = ws;                                  // 8M   bf16 x
  u16* wqkv_t = xb + (size_t)MROWS * 1024;           // 3M   [3072][1024]
  u16* wout_t = wqkv_t + (size_t)N3 * 1024;          // 1M   [1024][1024]
  u16* qbuf   = wout_t + (size_t)1024 * 1024;        // 8M   [bh][t][d]
  u16* kbuf   = qbuf + (size_t)MROWS * 1024;         // 8M   [bh][t][d]
  u16* vtbuf  = kbuf + (size_t)MROWS * 1024;         // 8M   [bh][d][t]
  u16* obuf   = vtbuf + (size_t)MROWS * 1024;        // 8M   [b][t][c]
  (void)ws_size; (void)n_in; (void)in_sizes; (void)out_size;

  int n4 = MROWS * 1024 / 4;
  cvt_f32_bf16<<<(n4 + 255) / 256, 256, 0, stream>>>(x, xb, n4);
  transpose_cvt<<<dim3(N3 / 32, 1024 / 32), dim3(32, 8), 0, stream>>>(Wqkv, wqkv_t, 1024, N3);
  transpose_cvt<<<dim3(1024 / 32, 1024 / 32), dim3(32, 8), 0, stream>>>(Wout, wout_t, 1024, 1024);
  gemm_qkv_kernel<<<dim3(N3 / 128, MROWS / 128), 256, 0, stream>>>(xb, wqkv_t, bqkv, qbuf, kbuf, vtbuf);
  attn_kernel<<<dim3(TSEQ / 64, BATCH * N_HEADS), 256, 0, stream>>>(qbuf, kbuf, vtbuf, obuf);
  gemm_out_kernel<<<dim3(1024 / 128, MROWS / 128), 256, 0, stream>>>(obuf, wout_t, bout, out);
}

// Round 6
// 336.248 us; speedup vs baseline: 1.9595x; 1.9508x over previous
//
#include <hip/hip_runtime.h>
#include <hip/hip_bf16.h>

// CausalSelfAttention on gfx950 — round 6.
// r4/r5 lesson: register prefetch is un-enforceable (compiler sank loads,
// VGPR=112 proves it); __syncthreads drains vmcnt(0) (r2/r3). Round-6 attn:
// LDS double-buffer K/V via global_load_lds DMA (cannot be sunk) with RAW
// s_barrier + fine-grained s_waitcnt vmcnt(4) inline asm — tile kt+1's DMA
// stays in flight across all of compute(kt); no vmcnt(0) drain anywhere in
// the loop. 128-row Q tiles, static-max softmax (no shuffles in loop),
// masked-fragment skip, heavy-first. GEMMs unchanged.

typedef unsigned short u16;
typedef __attribute__((ext_vector_type(8))) short short8;
typedef __attribute__((ext_vector_type(4))) float f32x4;

#define N_HEADS 16
#define HEAD_DIM 64
#define TSEQ 2048
#define BATCH 4
#define MROWS (BATCH * TSEQ)   // 8192
#define N3 3072                // 3*D_MODEL

__device__ __forceinline__ void cp16(const u16* g, u16* l) {
  __builtin_amdgcn_global_load_lds((const __attribute__((address_space(1))) void*)g,
                                   (__attribute__((address_space(3))) void*)l, 16, 0, 0);
}

__device__ __forceinline__ f32x4 mfma16(short8 a, short8 b, f32x4 c) {
  return __builtin_amdgcn_mfma_f32_16x16x32_bf16(a, b, c, 0, 0, 0);
}

__device__ __forceinline__ u16 f2b(float f) {
  __hip_bfloat16 h = __float2bfloat16(f);
  return *reinterpret_cast<u16*>(&h);
}

// ------------------------------------------------------------ fp32 -> bf16
__global__ __launch_bounds__(256) void cvt_f32_bf16(const float* __restrict__ src,
                                                    u16* __restrict__ dst, int n4) {
  int i = blockIdx.x * 256 + threadIdx.x;
  if (i < n4) {
    float4 v = *(const float4*)(src + (size_t)i * 4);
    u16* d = dst + (size_t)i * 4;
    d[0] = f2b(v.x); d[1] = f2b(v.y); d[2] = f2b(v.z); d[3] = f2b(v.w);
  }
}

// ------------------------------------------- fp32 [R][Cn] -> bf16 [Cn][R]
__global__ void transpose_cvt(const float* __restrict__ src, u16* __restrict__ dst,
                              int R, int Cn) {
  __shared__ float tile[32][33];
  int c0 = blockIdx.x * 32, r0 = blockIdx.y * 32;
  for (int i = threadIdx.y; i < 32; i += 8)
    tile[i][threadIdx.x] = src[(size_t)(r0 + i) * Cn + c0 + threadIdx.x];
  __syncthreads();
  for (int i = threadIdx.y; i < 32; i += 8)
    dst[(size_t)(c0 + i) * R + r0 + threadIdx.x] = f2b(tile[threadIdx.x][i]);
}

// ---------------------------------------------------------------- GEMM core
__device__ __forceinline__ void gemm128_core(const u16* __restrict__ A,
                                             const u16* __restrict__ Bt,
                                             int m0, int n0,
                                             u16* Asm, u16* Bsm,
                                             f32x4 acc[4][4]) {
  const int tid = threadIdx.x;
  const int w = tid >> 6;
  const int lane = tid & 63;
  const int quad = lane >> 4;
  const int l16 = lane & 15;
  const int wm = (w >> 1) * 64;
  const int wn = (w & 1) * 64;

#pragma unroll
  for (int i = 0; i < 4; ++i)
#pragma unroll
    for (int j = 0; j < 4; ++j) acc[i][j] = (f32x4){0.f, 0.f, 0.f, 0.f};

  for (int k0 = 0; k0 < 1024; k0 += 32) {
    __syncthreads();
#pragma unroll
    for (int p = 0; p < 2; ++p) {
      int s = p * 256 + tid;
      int row = s >> 2;
      int c4 = (s & 3) ^ ((row >> 1) & 3);
      cp16(A + (size_t)(m0 + row) * 1024 + k0 + c4 * 8,
           Asm + (size_t)(p * 256 + w * 64) * 8);
      cp16(Bt + (size_t)(n0 + row) * 1024 + k0 + c4 * 8,
           Bsm + (size_t)(p * 256 + w * 64) * 8);
    }
    __syncthreads();

    short8 a[4], b[4];
#pragma unroll
    for (int i = 0; i < 4; ++i) {
      int row = wm + i * 16 + l16;
      int c4 = quad ^ ((row >> 1) & 3);
      a[i] = *(const short8*)(Asm + row * 32 + c4 * 8);
    }
#pragma unroll
    for (int j = 0; j < 4; ++j) {
      int row = wn + j * 16 + l16;
      int c4 = quad ^ ((row >> 1) & 3);
      b[j] = *(const short8*)(Bsm + row * 32 + c4 * 8);
    }
#pragma unroll
    for (int i = 0; i < 4; ++i)
#pragma unroll
      for (int j = 0; j < 4; ++j)
        acc[i][j] = mfma16(a[i], b[j], acc[i][j]);
  }
}

// ---------------------------------------------------------------- QKV GEMM
__global__ __launch_bounds__(256) void gemm_qkv_kernel(
    const u16* __restrict__ x, const u16* __restrict__ Wt,
    const float* __restrict__ bias,
    u16* __restrict__ qb, u16* __restrict__ kb, u16* __restrict__ vtb) {
  __shared__ __align__(16) u16 Asm[128 * 32];
  __shared__ __align__(16) u16 Bsm[128 * 32];
  f32x4 acc[4][4];
  const int m0 = blockIdx.y * 128;
  const int n0 = blockIdx.x * 128;
  gemm128_core(x, Wt, m0, n0, Asm, Bsm, acc);

  const int tid = threadIdx.x;
  const int w = tid >> 6, lane = tid & 63, quad = lane >> 4, l16 = lane & 15;
  const int wm = (w >> 1) * 64, wn = (w & 1) * 64;
#pragma unroll
  for (int j = 0; j < 4; ++j) {
    int col = n0 + wn + j * 16 + l16;
    float bv = bias[col];
    int which = col >> 10;     // 0=q 1=k 2=v
    int rem = col & 1023;
    int h = rem >> 6, d = rem & 63;
#pragma unroll
    for (int i = 0; i < 4; ++i) {
#pragma unroll
      for (int r = 0; r < 4; ++r) {
        int m = m0 + wm + i * 16 + quad * 4 + r;
        int b_ = m >> 11, t = m & 2047;
        int bh = b_ * N_HEADS + h;
        u16 o = f2b(acc[i][j][r] + bv);
        if (which == 0)
          qb[((size_t)(bh * TSEQ + t) << 6) + d] = o;
        else if (which == 1)
          kb[((size_t)(bh * TSEQ + t) << 6) + d] = o;
        else
          vtb[((size_t)((bh << 6) + d)) * TSEQ + t] = o;
      }
    }
  }
}

// ---------------------------------------------------------------- attention
// One block per (128-row q-tile, bh). 4 waves; wave w, m-frag mi covers q rows
// qt*128 + mi*64 + w*16 .. +15. K-tile = 64 keys, LDS double-buffer, raw
// barriers + fine-grained vmcnt (never 0 mid-loop).
__global__ __launch_bounds__(256, 3) void attn_kernel(const u16* __restrict__ qb,
                                                      const u16* __restrict__ kb,
                                                      const u16* __restrict__ vtb,
                                                      u16* __restrict__ ob) {
  const int qt = (TSEQ / 128 - 1) - blockIdx.x;  // 15..0 — heavy blocks first
  const int bh = blockIdx.y;                     // 0..63
  __shared__ __align__(16) u16 Ksm[2][4096];     // [buf][t_k 64][d 64] swizzled
  __shared__ __align__(16) u16 Vsm[2][4096];     // [buf][d 64][t_k 64] swizzled
  __shared__ __align__(16) u16 Psm[4 * 32 * 72]; // per-wave P, stride 72 (pad)
  const int tid = threadIdx.x;
  const int w = tid >> 6, lane = tid & 63, quad = lane >> 4, l16 = lane & 15;
  const int qbase = qt * 128;

  // Q fragments (A-layout), in registers for the whole kernel
  short8 qf[2][2];
#pragma unroll
  for (int mi = 0; mi < 2; ++mi) {
    const u16* qr = qb + ((size_t)(bh * TSEQ + qbase + mi * 64 + w * 16 + l16)) * 64;
    qf[mi][0] = *(const short8*)(qr + quad * 8);
    qf[mi][1] = *(const short8*)(qr + 32 + quad * 8);
  }

  f32x4 o[2][4];
  float lp[2][4];
#pragma unroll
  for (int mi = 0; mi < 2; ++mi)
#pragma unroll
    for (int j = 0; j < 4; ++j) o[mi][j] = (f32x4){0.f, 0.f, 0.f, 0.f};
#pragma unroll
  for (int mi = 0; mi < 2; ++mi)
#pragma unroll
    for (int r = 0; r < 4; ++r) lp[mi][r] = 0.f;
  const float cexp = 0.18033688011112042f;  // (1/sqrt(64)) * log2(e)
  const float M = 10.0f;                    // static softmax shift

  const u16* kb_bh = kb + (size_t)bh * TSEQ * 64;
  const u16* vt_bh = vtb + (size_t)bh * 64 * TSEQ;
  u16* pw = Psm + w * 32 * 72;
  const int nk = 2 * qt + 2;

  // stage k-tile kt into buffer b: 4 DMA issues per thread (vmcnt +=4)
#define STAGE(kt_, b_)                                                        \
  do {                                                                        \
    const u16* kbase_ = kb_bh + (size_t)((kt_) * 64) * 64;                    \
    const u16* vbase_ = vt_bh + (kt_) * 64;                                   \
    _Pragma("unroll")                                                         \
    for (int p = 0; p < 2; ++p) {                                             \
      int s_ = p * 256 + tid;                                                 \
      int row_ = s_ >> 3;                                                     \
      int c8_ = (s_ & 7) ^ (row_ & 7);                                        \
      cp16(kbase_ + row_ * 64 + c8_ * 8, &Ksm[b_][(p * 256 + w * 64) * 8]);   \
      cp16(vbase_ + (size_t)row_ * TSEQ + c8_ * 8,                            \
           &Vsm[b_][(p * 256 + w * 64) * 8]);                                 \
    }                                                                         \
  } while (0)

  STAGE(0, 0);

  for (int kt = 0; kt < nk; ++kt) {
    // barrier 1: all waves finished READING buf((kt+1)&1) in iter kt-1
    asm volatile("s_barrier" ::: "memory");
    if (kt + 1 < nk) {
      STAGE(kt + 1, (kt + 1) & 1);               // DMA for kt+1 (stays in flight)
      asm volatile("s_waitcnt vmcnt(4)" ::: "memory");  // tile kt landed
    } else {
      asm volatile("s_waitcnt vmcnt(0)" ::: "memory");  // last tile: drain
    }
    // barrier 2: all waves' tile-kt DMA landed
    asm volatile("s_barrier" ::: "memory");

    const u16* Kb = Ksm[kt & 1];
    const u16* Vb = Vsm[kt & 1];

    bool act[2];
#pragma unroll
    for (int mi = 0; mi < 2; ++mi) {
      const int qmin = qbase + mi * 64 + w * 16;
      act[mi] = (kt * 64 <= qmin + 15);  // else whole fragment masked
      if (!act[mi]) continue;
      // S = Q K^T (16 q-rows x 64 k)
      f32x4 s[4];
#pragma unroll
      for (int j = 0; j < 4; ++j) {
        int row = j * 16 + l16;
        int ca = quad ^ (row & 7);
        int cb = (4 + quad) ^ (row & 7);
        short8 k0 = *(const short8*)(Kb + row * 64 + ca * 8);
        short8 k1 = *(const short8*)(Kb + row * 64 + cb * 8);
        f32x4 z = (f32x4){0.f, 0.f, 0.f, 0.f};
        z = mfma16(qf[mi][0], k0, z);
        z = mfma16(qf[mi][1], k1, z);
        s[j] = z;
      }
      if (kt * 64 + 63 > qmin) {  // diagonal overlap: elementwise causal mask
#pragma unroll
        for (int j = 0; j < 4; ++j) {
          int k = kt * 64 + j * 16 + l16;
#pragma unroll
          for (int r = 0; r < 4; ++r)
            if (k > qmin + quad * 4 + r) s[j][r] = -1e30f;
        }
      }
      // static-max softmax: p = exp2(s*cexp - M); per-lane partial sums
#pragma unroll
      for (int j = 0; j < 4; ++j) {
#pragma unroll
        for (int r = 0; r < 4; ++r) {
          float p_ = __builtin_amdgcn_exp2f(__builtin_fmaf(s[j][r], cexp, -M));
          lp[mi][r] += p_;
          pw[(mi * 16 + quad * 4 + r) * 72 + j * 16 + l16] = f2b(p_);
        }
      }
    }
    asm volatile("s_waitcnt lgkmcnt(0)" ::: "memory");  // P writes landed
#pragma unroll
    for (int mi = 0; mi < 2; ++mi) {
      if (!act[mi]) continue;
      short8 ap0 = *(const short8*)(pw + (mi * 16 + l16) * 72 + quad * 8);
      short8 ap1 = *(const short8*)(pw + (mi * 16 + l16) * 72 + 32 + quad * 8);
#pragma unroll
      for (int j = 0; j < 4; ++j) {
        int row = j * 16 + l16;  // d
        int ca = quad ^ (row & 7);
        int cb = (4 + quad) ^ (row & 7);
        short8 v0 = *(const short8*)(Vb + row * 64 + ca * 8);
        short8 v1 = *(const short8*)(Vb + row * 64 + cb * 8);
        o[mi][j] = mfma16(ap0, v0, o[mi][j]);
        o[mi][j] = mfma16(ap1, v1, o[mi][j]);
      }
    }
  }
#undef STAGE

  // epilogue: reduce l across the 16 lanes sharing quad, normalize, store
#pragma unroll
  for (int mi = 0; mi < 2; ++mi)
#pragma unroll
    for (int r = 0; r < 4; ++r) {
      lp[mi][r] += __shfl_xor(lp[mi][r], 1);
      lp[mi][r] += __shfl_xor(lp[mi][r], 2);
      lp[mi][r] += __shfl_xor(lp[mi][r], 4);
      lp[mi][r] += __shfl_xor(lp[mi][r], 8);
    }
  const int b_ = bh >> 4, h = bh & 15;
#pragma unroll
  for (int mi = 0; mi < 2; ++mi)
#pragma unroll
    for (int j = 0; j < 4; ++j)
#pragma unroll
      for (int r = 0; r < 4; ++r) {
        int t = qbase + mi * 64 + w * 16 + quad * 4 + r;
        int d = j * 16 + l16;
        ob[((size_t)(b_ * TSEQ + t)) * 1024 + h * 64 + d] =
            f2b(o[mi][j][r] / lp[mi][r]);
      }
}

// ------------------------------------------------------- out GEMM (fp32 out)
__global__ __launch_bounds__(256) void gemm_out_kernel(
    const u16* __restrict__ attn, const u16* __restrict__ Wt,
    const float* __restrict__ bias, float* __restrict__ out) {
  __shared__ __align__(16) u16 Asm[128 * 32];
  __shared__ __align__(16) u16 Bsm[128 * 32];
  f32x4 acc[4][4];
  const int m0 = blockIdx.y * 128;
  const int n0 = blockIdx.x * 128;
  gemm128_core(attn, Wt, m0, n0, Asm, Bsm, acc);

  const int tid = threadIdx.x;
  const int w = tid >> 6, lane = tid & 63, quad = lane >> 4, l16 = lane & 15;
  const int wm = (w >> 1) * 64, wn = (w & 1) * 64;
#pragma unroll
  for (int j = 0; j < 4; ++j) {
    int col = n0 + wn + j * 16 + l16;
    float bv = bias[col];
#pragma unroll
    for (int i = 0; i < 4; ++i)
#pragma unroll
      for (int r = 0; r < 4; ++r) {
        int m = m0 + wm + i * 16 + quad * 4 + r;
        out[(size_t)m * 1024 + col] = acc[i][j][r] + bv;
      }
  }
}

// ---------------------------------------------------------------- launcher
extern "C" void kernel_launch(void* const* d_in, const int* in_sizes, int n_in,
                              void* d_out, int out_size, void* d_ws, size_t ws_size,
                              hipStream_t stream) {
  const float* x    = (const float*)d_in[0];   // [8192][1024] fp32
  const float* Wqkv = (const float*)d_in[1];   // [1024][3072] fp32
  const float* bqkv = (const float*)d_in[2];   // [3072] fp32
  const float* Wout = (const float*)d_in[3];   // [1024][1024] fp32
  const float* bout = (const float*)d_in[4];   // [1024] fp32
  float* out = (float*)d_out;                  // [8192][1024] fp32

  u16* ws = (u16*)d_ws;
  u16* xb     = ws;                                  // 8M   bf16 x
  u16* wqkv_t = xb + (size_t)MROWS * 1024;           // 3M   [3072][1024]
  u16* wout_t = wqkv_t + (size_t)N3 * 1024;          // 1M   [1024][1024]
  u16* qbuf   = wout_t + (size_t)1024 * 1024;        // 8M   [bh][t][d]
  u16* kbuf   = qbuf + (size_t)MROWS * 1024;         // 8M   [bh][t][d]
  u16* vtbuf  = kbuf + (size_t)MROWS * 1024;         // 8M   [bh][d][t]
  u16* obuf   = vtbuf + (size_t)MROWS * 1024;        // 8M   [b][t][c]
  (void)ws_size; (void)n_in; (void)in_sizes; (void)out_size;

  int n4 = MROWS * 1024 / 4;
  cvt_f32_bf16<<<(n4 + 255) / 256, 256, 0, stream>>>(x, xb, n4);
  transpose_cvt<<<dim3(N3 / 32, 1024 / 32), dim3(32, 8), 0, stream>>>(Wqkv, wqkv_t, 1024, N3);
  transpose_cvt<<<dim3(1024 / 32, 1024 / 32), dim3(32, 8), 0, stream>>>(Wout, wout_t, 1024, 1024);
  gemm_qkv_kernel<<<dim3(N3 / 128, MROWS / 128), 256, 0, stream>>>(xb, wqkv_t, bqkv, qbuf, kbuf, vtbuf);
  attn_kernel<<<dim3(TSEQ / 128, BATCH * N_HEADS), 256, 0, stream>>>(qbuf, kbuf, vtbuf, obuf);
  gemm_out_kernel<<<dim3(1024 / 128, MROWS / 128), 256, 0, stream>>>(obuf, wout_t, bout, out);
}